// Round 1
// baseline (50.747 us; speedup 1.0000x reference)
//
#include <hip/hip_runtime.h>

// BertWordEmbedder: B=64, T=512, H=768, W=256, D=256
// out[b,w,d] = (mean_{t: wid[b,t]==w} hs[b,t,:]) @ proj_w + proj_b
// word_ids sorted per row -> contiguous token segments -> binary search bounds.
// Fused: pool into LDS (bf16), then MFMA GEMM against pre-transposed bf16 W.

#define NB 64
#define NT 512
#define NH 768
#define NW 256
#define ND 256
#define WT 32            // words per block
#define PAD 8            // +8 bf16 = 16B pad -> row stride 1552B, kills LDS bank conflicts
#define ROWE (NH + PAD)  // 776 ushorts per pooled row

typedef __attribute__((ext_vector_type(8))) short short8;       // 8 bf16 (4 VGPRs) MFMA A/B frag
typedef __attribute__((ext_vector_type(4))) float f32x4;        // MFMA C/D frag
typedef __attribute__((ext_vector_type(4))) float float4v;
typedef __attribute__((ext_vector_type(4))) unsigned short ushort4v;

__device__ __forceinline__ unsigned short f2bf(float f) {
    union { float f; unsigned u; } v; v.f = f;
    unsigned r = v.u + 0x7fffu + ((v.u >> 16) & 1u);  // RNE
    return (unsigned short)(r >> 16);
}

// Transpose + convert proj_w [H=768][D=256] fp32 -> Wt [D=256][H=768] bf16 (in d_ws)
__global__ void prep_wt(const float* __restrict__ w, unsigned short* __restrict__ wt) {
    __shared__ float tile[32][33];
    int tx = threadIdx.x & 31, ty = threadIdx.x >> 5;  // 256 thr: ty 0..7
    int k0 = blockIdx.x * 32, n0 = blockIdx.y * 32;
    #pragma unroll
    for (int i = 0; i < 4; ++i)
        tile[ty + 8 * i][tx] = w[(size_t)(k0 + ty + 8 * i) * ND + n0 + tx];
    __syncthreads();
    #pragma unroll
    for (int i = 0; i < 4; ++i)
        wt[(size_t)(n0 + ty + 8 * i) * NH + k0 + tx] = f2bf(tile[tx][ty + 8 * i]);
}

__global__ __launch_bounds__(256, 2)
void bert_pool_proj(const float* __restrict__ hs, const int* __restrict__ wid,
                    const unsigned short* __restrict__ wt, const float* __restrict__ bias,
                    float* __restrict__ out) {
    __shared__ int s_wid[NT];
    __shared__ int s_bound[WT + 1];
    __shared__ unsigned short s_pool[WT][ROWE];

    const int tid  = threadIdx.x;
    const int b    = blockIdx.x >> 3;          // 8 word-groups per batch
    const int w0   = (blockIdx.x & 7) * WT;
    const int lane = tid & 63;
    const int wave = tid >> 6;

    // stage word ids (512 ints)
    s_wid[tid]       = wid[b * NT + tid];
    s_wid[tid + 256] = wid[b * NT + tid + 256];
    __syncthreads();

    // segment bounds via lower_bound (33 threads)
    if (tid <= WT) {
        int v = w0 + tid;
        int lo = 0, hi = NT;
        while (lo < hi) { int mid = (lo + hi) >> 1; if (s_wid[mid] < v) lo = mid + 1; else hi = mid; }
        s_bound[tid] = lo;
    }
    __syncthreads();

    // ---- Phase A: segment-mean pooling into LDS (bf16) ----
    // wave handles words wave, wave+4, ... ; lane covers 4 consecutive h (float4)
    for (int wi = wave; wi < WT; wi += 4) {
        int s = s_bound[wi], e = s_bound[wi + 1];
        float acc[3][4];
        #pragma unroll
        for (int k = 0; k < 3; ++k)
            #pragma unroll
            for (int j = 0; j < 4; ++j) acc[k][j] = 0.f;
        for (int t = s; t < e; ++t) {
            const float4v* p = (const float4v*)(hs + ((size_t)b * NT + t) * NH);
            #pragma unroll
            for (int k = 0; k < 3; ++k) {
                float4v v = p[k * 64 + lane];   // h = k*256 + lane*4, coalesced 1KB/wave
                acc[k][0] += v[0]; acc[k][1] += v[1]; acc[k][2] += v[2]; acc[k][3] += v[3];
            }
        }
        int cnt = e - s; if (cnt < 1) cnt = 1;
        float scale = 1.0f / (float)cnt;        // empty word -> zeros (sums are 0)
        #pragma unroll
        for (int k = 0; k < 3; ++k) {
            ushort4v u;
            u[0] = f2bf(acc[k][0] * scale); u[1] = f2bf(acc[k][1] * scale);
            u[2] = f2bf(acc[k][2] * scale); u[3] = f2bf(acc[k][3] * scale);
            *(ushort4v*)&s_pool[wi][k * 256 + lane * 4] = u;  // 8B store, conflict-free
        }
    }
    __syncthreads();

    // ---- Phase B: [32 x 768] x [768 x 256] MFMA GEMM ----
    // wave owns 64 output cols (4 N-tiles), both 16-row M-tiles.
    const int colg = wave * 64;
    const int cl   = lane & 15;      // col within 16-tile / A row
    const int kg   = lane >> 4;      // k-group (8 elems each)

    float bv[4];
    #pragma unroll
    for (int nt = 0; nt < 4; ++nt) bv[nt] = bias[colg + nt * 16 + cl];

    f32x4 acc[2][4];
    #pragma unroll
    for (int mt = 0; mt < 2; ++mt)
        #pragma unroll
        for (int nt = 0; nt < 4; ++nt)
            #pragma unroll
            for (int r = 0; r < 4; ++r) acc[mt][nt][r] = 0.f;

    for (int ks = 0; ks < NH / 32; ++ks) {      // 24 K-steps
        const int kof = ks * 32 + kg * 8;
        short8 a0 = *(const short8*)&s_pool[cl][kof];
        short8 a1 = *(const short8*)&s_pool[16 + cl][kof];
        #pragma unroll
        for (int nt = 0; nt < 4; ++nt) {
            short8 bf = *(const short8*)&wt[(size_t)(colg + nt * 16 + cl) * NH + kof];
            acc[0][nt] = __builtin_amdgcn_mfma_f32_16x16x32_bf16(a0, bf, acc[0][nt], 0, 0, 0);
            acc[1][nt] = __builtin_amdgcn_mfma_f32_16x16x32_bf16(a1, bf, acc[1][nt], 0, 0, 0);
        }
    }

    // epilogue: C/D layout col=lane&15, row=(lane>>4)*4+r  [m89-verified]
    #pragma unroll
    for (int mt = 0; mt < 2; ++mt)
        #pragma unroll
        for (int nt = 0; nt < 4; ++nt)
            #pragma unroll
            for (int r = 0; r < 4; ++r) {
                int wrow = w0 + mt * 16 + kg * 4 + r;
                out[((size_t)b * NW + wrow) * ND + colg + nt * 16 + cl] = acc[mt][nt][r] + bv[nt];
            }
}

extern "C" void kernel_launch(void* const* d_in, const int* in_sizes, int n_in,
                              void* d_out, int out_size, void* d_ws, size_t ws_size,
                              hipStream_t stream) {
    const float* hs  = (const float*)d_in[0];
    const int*   wid = (const int*)d_in[1];
    const float* pw  = (const float*)d_in[2];
    const float* pb  = (const float*)d_in[3];
    float* out = (float*)d_out;
    unsigned short* wt = (unsigned short*)d_ws;   // 256*768*2 = 393216 B

    dim3 gp(NH / 32, ND / 32);
    prep_wt<<<gp, 256, 0, stream>>>(pw, wt);
    bert_pool_proj<<<NB * (NW / WT), 256, 0, stream>>>(hs, wid, wt, pb, out);
}